// Round 1
// baseline (432.732 us; speedup 1.0000x reference)
//
#include <hip/hip_runtime.h>
#include <hip/hip_bf16.h>

// Problem constants
#define HH 256
#define WW 256
#define CCH 1024
#define NB 2
#define HF 32
#define WF 32
#define PP 1024   // HF*WF patches per image

using f32x4 = __attribute__((ext_vector_type(4))) float;
using short8 = __attribute__((ext_vector_type(8))) short;

// ---------------------------------------------------------------------------
// K1: patch average pool.  One block per (b, c, ph) slab: 8 rows x 256 cols.
// Coalesced float4 reads; LDS reduce to 32 patch means; writes y[b][c][p] f32.
// ---------------------------------------------------------------------------
__global__ __launch_bounds__(256) void pool_kernel(const float* __restrict__ x,
                                                   float* __restrict__ y) {
    int blk = blockIdx.x;            // (b*1024 + c)*32 + ph
    int ph  = blk & 31;
    int bc  = blk >> 5;              // b*1024 + c
    int t   = threadIdx.x;
    const float* xp = x + ((size_t)bc * HH + (size_t)ph * 8) * WW;
    int r    = t >> 6;               // 0..3
    int col4 = (t & 63) * 4;         // 0..252
    float s = 0.f;
#pragma unroll
    for (int it = 0; it < 2; ++it) {
        float4 v = *(const float4*)(xp + (size_t)(r + it * 4) * WW + col4);
        s += v.x + v.y + v.z + v.w;
    }
    __shared__ float red[256];
    red[t] = s;
    __syncthreads();
    if (t < 32) {
        float tot = 0.f;
#pragma unroll
        for (int r4 = 0; r4 < 4; ++r4)
            tot += red[r4 * 64 + 2 * t] + red[r4 * 64 + 2 * t + 1];
        y[(size_t)bc * PP + ph * WF + t] = tot * (1.f / 64.f);
    }
}

// ---------------------------------------------------------------------------
// K2: conv weight f32 [co][ci][3] -> bf16 wT[tap][co][ci] (3 planes of 1M).
// ---------------------------------------------------------------------------
__global__ __launch_bounds__(256) void wconv_kernel(const float* __restrict__ w,
                                                    __hip_bfloat16* __restrict__ wT) {
    int tid = blockIdx.x * 256 + threadIdx.x;   // co*1024 + ci
    const float* p = w + (size_t)tid * 3;
    float a = p[0], b = p[1], c = p[2];
    wT[tid]               = __float2bfloat16(a);
    wT[(1u << 20) + tid]  = __float2bfloat16(b);
    wT[(2u << 20) + tid]  = __float2bfloat16(c);
}

// ---------------------------------------------------------------------------
// K3: zero the pad rows of yT (p = -1 and p = 1024).
// ---------------------------------------------------------------------------
__global__ __launch_bounds__(256) void pad_kernel(__hip_bfloat16* __restrict__ yT) {
    int tid = blockIdx.x * 256 + threadIdx.x;   // 2048 threads: b*1024 + c
    int b = tid >> 10, c = tid & 1023;
    __hip_bfloat16 z = __float2bfloat16(0.f);
    __hip_bfloat16* base = yT + (size_t)b * (PP + 2) * CCH;
    base[c] = z;
    base[(size_t)(PP + 1) * CCH + c] = z;
}

// ---------------------------------------------------------------------------
// K4: transpose+convert y[b][c][p] f32 -> yT[b][1+p][c] bf16 (32x32 LDS tiles)
// ---------------------------------------------------------------------------
__global__ __launch_bounds__(256) void transpose_kernel(const float* __restrict__ y,
                                                        __hip_bfloat16* __restrict__ yT) {
    int b  = blockIdx.z;
    int c0 = blockIdx.x * 32;
    int p0 = blockIdx.y * 32;
    __shared__ float tile[32][33];
    int tx = threadIdx.x, ty = threadIdx.y;    // 32 x 8
    const float* yb = y + (size_t)b * CCH * PP;
#pragma unroll
    for (int rr = 0; rr < 4; ++rr)
        tile[ty + rr * 8][tx] = yb[(size_t)(c0 + ty + rr * 8) * PP + p0 + tx];
    __syncthreads();
    __hip_bfloat16* yTb = yT + (size_t)b * (PP + 2) * CCH;
#pragma unroll
    for (int rr = 0; rr < 4; ++rr)
        yTb[(size_t)(1 + p0 + ty + rr * 8) * CCH + c0 + tx] =
            __float2bfloat16(tile[tx][ty + rr * 8]);
}

// ---------------------------------------------------------------------------
// K5: conv-as-GEMM with bf16 MFMA.  g[b,co,p] = sum_{tap,ci} wT[tap][co][ci] *
// y[b][ci][p+tap-1], then sigmoid -> gate[b][co][p] f32.
// Block = 64x64 output tile, 4 waves in 2x2, each wave 32x32 (2x2 fragments).
// A/B fragments loaded directly from global (w: 6 MiB, y: 2 MiB -> L2-hit).
// ---------------------------------------------------------------------------
__global__ __launch_bounds__(256) void conv_gemm_kernel(
        const __hip_bfloat16* __restrict__ wT,
        const __hip_bfloat16* __restrict__ yT,
        float* __restrict__ gate) {
    int lane = threadIdx.x & 63;
    int wid  = threadIdx.x >> 6;
    int wr = wid >> 1, wc = wid & 1;
    int l15 = lane & 15, lhi = lane >> 4;       // lhi: 0..3
    int co_base = blockIdx.x * 64 + wr * 32;
    int p_base  = blockIdx.y * 64 + wc * 32;
    int b = blockIdx.z;
    const __hip_bfloat16* yTb = yT + (size_t)b * (PP + 2) * CCH;

    f32x4 acc[2][2] = {};
    for (int tap = 0; tap < 3; ++tap) {
        // A: lane reads w rows co_base + l15 (+16), k-chunk lhi*8, contiguous in ci
        const __hip_bfloat16* Ap = wT + (size_t)tap * (1u << 20)
                                 + (size_t)(co_base + l15) * CCH + lhi * 8;
        // B: padded row (p + tap) holds y[:, p + tap - 1]; zero rows at edges
        const __hip_bfloat16* Bp = yTb + (size_t)(p_base + l15 + tap) * CCH + lhi * 8;
        for (int ci0 = 0; ci0 < CCH; ci0 += 32) {
            short8 a0 = *(const short8*)(Ap + ci0);
            short8 a1 = *(const short8*)(Ap + ci0 + 16 * CCH);
            short8 b0 = *(const short8*)(Bp + ci0);
            short8 b1 = *(const short8*)(Bp + ci0 + 16 * CCH);
            acc[0][0] = __builtin_amdgcn_mfma_f32_16x16x32_bf16(a0, b0, acc[0][0], 0, 0, 0);
            acc[0][1] = __builtin_amdgcn_mfma_f32_16x16x32_bf16(a0, b1, acc[0][1], 0, 0, 0);
            acc[1][0] = __builtin_amdgcn_mfma_f32_16x16x32_bf16(a1, b0, acc[1][0], 0, 0, 0);
            acc[1][1] = __builtin_amdgcn_mfma_f32_16x16x32_bf16(a1, b1, acc[1][1], 0, 0, 0);
        }
    }
    // Epilogue: sigmoid, store gate f32.  C/D layout: col = lane&15,
    // row = (lane>>4)*4 + reg  [measured m89/m91].
    float* gb = gate + (size_t)b * CCH * PP;
#pragma unroll
    for (int i16 = 0; i16 < 2; ++i16) {
#pragma unroll
        for (int j16 = 0; j16 < 2; ++j16) {
            int col  = p_base + j16 * 16 + l15;
            int row0 = co_base + i16 * 16 + lhi * 4;
#pragma unroll
            for (int r = 0; r < 4; ++r) {
                float v = acc[i16][j16][r];
                gb[(size_t)(row0 + r) * PP + col] = 1.f / (1.f + __expf(-v));
            }
        }
    }
}

// ---------------------------------------------------------------------------
// K6: out = x * gate[b][c][p(h,w)].  float4 grid-stride; one gate per float4.
// ---------------------------------------------------------------------------
__global__ __launch_bounds__(256) void apply_kernel(const float* __restrict__ x,
                                                    const float* __restrict__ gate,
                                                    float* __restrict__ out) {
    size_t i0 = (size_t)blockIdx.x * blockDim.x + threadIdx.x;
    size_t stride = (size_t)gridDim.x * blockDim.x;
    const size_t total4 = (size_t)1 << 25;   // 2*1024*256*256 / 4
    for (size_t i4 = i0; i4 < total4; i4 += stride) {
        int w4 = (int)(i4 & 63);             // float4 index within row (W/4=64)
        int h  = (int)((i4 >> 6) & 255);
        int c  = (int)((i4 >> 14) & 1023);
        int b  = (int)(i4 >> 24);
        int p  = (h >> 3) * 32 + (w4 >> 1);  // 4 floats never straddle a patch
        float g = gate[(((size_t)b * 1024 + c) << 10) + p];
        float4 v = ((const float4*)x)[i4];
        float4 o;
        o.x = v.x * g; o.y = v.y * g; o.z = v.z * g; o.w = v.w * g;
        ((float4*)out)[i4] = o;
    }
}

extern "C" void kernel_launch(void* const* d_in, const int* in_sizes, int n_in,
                              void* d_out, int out_size, void* d_ws, size_t ws_size,
                              hipStream_t stream) {
    const float* x = (const float*)d_in[0];       // [2,1024,256,256] f32
    const float* w = (const float*)d_in[1];       // [1024,1024,3] f32
    float* out = (float*)d_out;                   // [2,1024,256,256] f32

    // Workspace layout (all offsets 256-aligned):
    //   y    f32  [2][1024][1024]        8,388,608 B @ 0
    //   yT   bf16 [2][1026][1024]        4,202,496 B @ 8,388,608
    //   wT   bf16 [3][1024][1024]        6,291,456 B @ 12,591,104
    //   gate f32  [2][1024][1024]        8,388,608 B @ 18,882,560   (tot ~26 MiB)
    char* ws = (char*)d_ws;
    float*          y    = (float*)(ws);
    __hip_bfloat16* yT   = (__hip_bfloat16*)(ws + 8388608);
    __hip_bfloat16* wT   = (__hip_bfloat16*)(ws + 12591104);
    float*          gate = (float*)(ws + 18882560);

    hipLaunchKernelGGL(pool_kernel,      dim3(65536),      dim3(256),    0, stream, x, y);
    hipLaunchKernelGGL(wconv_kernel,     dim3(4096),       dim3(256),    0, stream, w, wT);
    hipLaunchKernelGGL(pad_kernel,       dim3(8),          dim3(256),    0, stream, yT);
    hipLaunchKernelGGL(transpose_kernel, dim3(32, 32, 2),  dim3(32, 8),  0, stream, y, yT);
    hipLaunchKernelGGL(conv_gemm_kernel, dim3(16, 16, 2),  dim3(256),    0, stream, wT, yT, gate);
    hipLaunchKernelGGL(apply_kernel,     dim3(2048),       dim3(256),    0, stream, x, gate, out);
}

// Round 3
// 426.475 us; speedup vs baseline: 1.0147x; 1.0147x over previous
//
#include <hip/hip_runtime.h>
#include <hip/hip_bf16.h>

// Problem constants
#define HH 256
#define WW 256
#define CCH 1024
#define NB 2
#define HF 32
#define WF 32
#define PP 1024   // HF*WF patches per image

using f32x4 = __attribute__((ext_vector_type(4))) float;
using short8 = __attribute__((ext_vector_type(8))) short;

// ---------------------------------------------------------------------------
// K1: patch average pool.  One block per (b, c, ph) slab: 8 rows x 256 cols.
// Coalesced ext-vector float4 reads (non-temporal: x streamed, no reuse);
// LDS reduce to 32 patch means; writes y[b][c][p] f32.
// ---------------------------------------------------------------------------
__global__ __launch_bounds__(256) void pool_kernel(const float* __restrict__ x,
                                                   float* __restrict__ y) {
    int blk = blockIdx.x;            // (b*1024 + c)*32 + ph
    int ph  = blk & 31;
    int bc  = blk >> 5;              // b*1024 + c
    int t   = threadIdx.x;
    const float* xp = x + ((size_t)bc * HH + (size_t)ph * 8) * WW;
    int r    = t >> 6;               // 0..3
    int col4 = (t & 63) * 4;         // 0..252
    float s = 0.f;
#pragma unroll
    for (int it = 0; it < 2; ++it) {
        f32x4 v = __builtin_nontemporal_load(
            (const f32x4*)(xp + (size_t)(r + it * 4) * WW + col4));
        s += v.x + v.y + v.z + v.w;
    }
    __shared__ float red[256];
    red[t] = s;
    __syncthreads();
    if (t < 32) {
        float tot = 0.f;
#pragma unroll
        for (int r4 = 0; r4 < 4; ++r4)
            tot += red[r4 * 64 + 2 * t] + red[r4 * 64 + 2 * t + 1];
        y[(size_t)bc * PP + ph * WF + t] = tot * (1.f / 64.f);
    }
}

// ---------------------------------------------------------------------------
// K2: conv weight f32 [co][ci][3] -> bf16 wT[tap][co][ci] (3 planes of 1M),
// plus zero the pad rows of yT (p = -1 and p = 1024) in the first 2048 threads.
// ---------------------------------------------------------------------------
__global__ __launch_bounds__(256) void wconv_pad_kernel(const float* __restrict__ w,
                                                        __hip_bfloat16* __restrict__ wT,
                                                        __hip_bfloat16* __restrict__ yT) {
    int tid = blockIdx.x * 256 + threadIdx.x;   // co*1024 + ci
    const float* p = w + (size_t)tid * 3;
    float a = p[0], b = p[1], c = p[2];
    wT[tid]               = __float2bfloat16(a);
    wT[(1u << 20) + tid]  = __float2bfloat16(b);
    wT[(2u << 20) + tid]  = __float2bfloat16(c);
    if (tid < 2 * CCH) {
        int bb = tid >> 10, cc = tid & 1023;
        __hip_bfloat16 z = __float2bfloat16(0.f);
        __hip_bfloat16* base = yT + (size_t)bb * (PP + 2) * CCH;
        base[cc] = z;
        base[(size_t)(PP + 1) * CCH + cc] = z;
    }
}

// ---------------------------------------------------------------------------
// K3: transpose+convert y[b][c][p] f32 -> yT[b][1+p][c] bf16 (32x32 LDS tiles)
// ---------------------------------------------------------------------------
__global__ __launch_bounds__(256) void transpose_kernel(const float* __restrict__ y,
                                                        __hip_bfloat16* __restrict__ yT) {
    int b  = blockIdx.z;
    int c0 = blockIdx.x * 32;
    int p0 = blockIdx.y * 32;
    __shared__ float tile[32][33];
    int tx = threadIdx.x, ty = threadIdx.y;    // 32 x 8
    const float* yb = y + (size_t)b * CCH * PP;
#pragma unroll
    for (int rr = 0; rr < 4; ++rr)
        tile[ty + rr * 8][tx] = yb[(size_t)(c0 + ty + rr * 8) * PP + p0 + tx];
    __syncthreads();
    __hip_bfloat16* yTb = yT + (size_t)b * (PP + 2) * CCH;
#pragma unroll
    for (int rr = 0; rr < 4; ++rr)
        yTb[(size_t)(1 + p0 + ty + rr * 8) * CCH + c0 + tx] =
            __float2bfloat16(tile[tx][ty + rr * 8]);
}

// ---------------------------------------------------------------------------
// K4: conv-as-GEMM, bf16 MFMA, restructured for occupancy.
// Wave tile = 16(co) x 32(p); block = 4 waves stacked along co (64 x 32 tile).
// Grid = 16 x 32 x 2 = 1024 blocks -> 4096 waves -> 4 waves/SIMD (was 2).
// Per K-chunk: 1 A-load + 2 B-loads + 2 MFMA; all 4 waves share B rows (L1).
// ---------------------------------------------------------------------------
__global__ __launch_bounds__(256) void conv_gemm_kernel(
        const __hip_bfloat16* __restrict__ wT,
        const __hip_bfloat16* __restrict__ yT,
        float* __restrict__ gate) {
    int lane = threadIdx.x & 63;
    int wid  = threadIdx.x >> 6;
    int l15 = lane & 15, lhi = lane >> 4;       // lhi: 0..3
    int co_base = blockIdx.x * 64 + wid * 16;
    int p_base  = blockIdx.y * 32;
    int b = blockIdx.z;
    const __hip_bfloat16* yTb = yT + (size_t)b * (PP + 2) * CCH;

    f32x4 acc[2] = {};
#pragma unroll
    for (int tap = 0; tap < 3; ++tap) {
        const __hip_bfloat16* Ap = wT + (size_t)tap * (1u << 20)
                                 + (size_t)(co_base + l15) * CCH + lhi * 8;
        const __hip_bfloat16* Bp = yTb + (size_t)(p_base + l15 + tap) * CCH + lhi * 8;
        for (int ci0 = 0; ci0 < CCH; ci0 += 32) {
            short8 a0 = *(const short8*)(Ap + ci0);
            short8 b0 = *(const short8*)(Bp + ci0);
            short8 b1 = *(const short8*)(Bp + ci0 + 16 * CCH);
            acc[0] = __builtin_amdgcn_mfma_f32_16x16x32_bf16(a0, b0, acc[0], 0, 0, 0);
            acc[1] = __builtin_amdgcn_mfma_f32_16x16x32_bf16(a0, b1, acc[1], 0, 0, 0);
        }
    }
    // Epilogue: sigmoid, store gate f32.  C/D layout: col = lane&15,
    // row = (lane>>4)*4 + reg  [measured m89/m91].
    float* gb = gate + (size_t)b * CCH * PP;
#pragma unroll
    for (int j16 = 0; j16 < 2; ++j16) {
        int col  = p_base + j16 * 16 + l15;
        int row0 = co_base + lhi * 4;
#pragma unroll
        for (int r = 0; r < 4; ++r) {
            float v = acc[j16][r];
            gb[(size_t)(row0 + r) * PP + col] = 1.f / (1.f + __expf(-v));
        }
    }
}

// ---------------------------------------------------------------------------
// K5: out = x * gate[b][c][p(h,w)].  f32x4 grid-stride; one gate per float4.
// Non-temporal on the big streams; gate reads stay cached.
// ---------------------------------------------------------------------------
__global__ __launch_bounds__(256) void apply_kernel(const float* __restrict__ x,
                                                    const float* __restrict__ gate,
                                                    float* __restrict__ out) {
    size_t i0 = (size_t)blockIdx.x * blockDim.x + threadIdx.x;
    size_t stride = (size_t)gridDim.x * blockDim.x;
    const size_t total4 = (size_t)1 << 25;   // 2*1024*256*256 / 4
    for (size_t i4 = i0; i4 < total4; i4 += stride) {
        int w4 = (int)(i4 & 63);             // float4 index within row (W/4=64)
        int h  = (int)((i4 >> 6) & 255);
        int c  = (int)((i4 >> 14) & 1023);
        int b  = (int)(i4 >> 24);
        int p  = (h >> 3) * 32 + (w4 >> 1);  // 4 floats never straddle a patch
        float g = gate[(((size_t)b * 1024 + c) << 10) + p];
        f32x4 v = __builtin_nontemporal_load((const f32x4*)x + i4);
        v *= g;
        __builtin_nontemporal_store(v, (f32x4*)out + i4);
    }
}

extern "C" void kernel_launch(void* const* d_in, const int* in_sizes, int n_in,
                              void* d_out, int out_size, void* d_ws, size_t ws_size,
                              hipStream_t stream) {
    const float* x = (const float*)d_in[0];       // [2,1024,256,256] f32
    const float* w = (const float*)d_in[1];       // [1024,1024,3] f32
    float* out = (float*)d_out;                   // [2,1024,256,256] f32

    // Workspace layout (all offsets 256-aligned):
    //   y    f32  [2][1024][1024]        8,388,608 B @ 0
    //   yT   bf16 [2][1026][1024]        4,202,496 B @ 8,388,608
    //   wT   bf16 [3][1024][1024]        6,291,456 B @ 12,591,104
    //   gate f32  [2][1024][1024]        8,388,608 B @ 18,882,560   (tot ~26 MiB)
    char* ws = (char*)d_ws;
    float*          y    = (float*)(ws);
    __hip_bfloat16* yT   = (__hip_bfloat16*)(ws + 8388608);
    __hip_bfloat16* wT   = (__hip_bfloat16*)(ws + 12591104);
    float*          gate = (float*)(ws + 18882560);

    hipLaunchKernelGGL(pool_kernel,      dim3(65536),      dim3(256),    0, stream, x, y);
    hipLaunchKernelGGL(wconv_pad_kernel, dim3(4096),       dim3(256),    0, stream, w, wT, yT);
    hipLaunchKernelGGL(transpose_kernel, dim3(32, 32, 2),  dim3(32, 8),  0, stream, y, yT);
    hipLaunchKernelGGL(conv_gemm_kernel, dim3(16, 32, 2),  dim3(256),    0, stream, wT, yT, gate);
    hipLaunchKernelGGL(apply_kernel,     dim3(2048),       dim3(256),    0, stream, x, gate, out);
}